// Round 3
// baseline (464.812 us; speedup 1.0000x reference)
//
#include <hip/hip_runtime.h>
#include <hip/hip_bf16.h>

typedef __attribute__((ext_vector_type(4))) float floatx4;
typedef __attribute__((ext_vector_type(2))) float floatx2;
typedef __attribute__((ext_vector_type(8))) short shortx8;

__device__ __forceinline__ unsigned short f2bf(float f) {
    unsigned int u; __builtin_memcpy(&u, &f, 4);
    u += 0x7FFFu + ((u >> 16) & 1u);   // RNE
    return (unsigned short)(u >> 16);
}
__device__ __forceinline__ float bf2f(unsigned short h) {
    unsigned int u = ((unsigned int)h) << 16;
    float f; __builtin_memcpy(&f, &u, 4); return f;
}
__device__ __forceinline__ shortx8 pack8(floatx4 lo, floatx4 hi) {
    shortx8 r;
    r[0] = (short)f2bf(lo[0]); r[1] = (short)f2bf(lo[1]);
    r[2] = (short)f2bf(lo[2]); r[3] = (short)f2bf(lo[3]);
    r[4] = (short)f2bf(hi[0]); r[5] = (short)f2bf(hi[1]);
    r[6] = (short)f2bf(hi[2]); r[7] = (short)f2bf(hi[3]);
    return r;
}

#define BM 128
#define BN 128
#define BK 32

// q/k/v = X (MxK fp32) * W^T (W NxK fp32) + bias. Inputs cast fp32->bf16 (RNE)
// during staging; MFMA bf16, fp32 accumulate. z==0 writes q as FP32 (to d_out);
// z==1/2 write k/v as BF16 (workspace) to halve sampler traffic.
__global__ __launch_bounds__(256) void gemm_qkv(
    const float* __restrict__ X,
    const float* __restrict__ Wq, const float* __restrict__ Wk,
    const float* __restrict__ Wv,
    const float* __restrict__ bq, const float* __restrict__ bk,
    const float* __restrict__ bv,
    float* __restrict__ Qf, unsigned short* __restrict__ Kb,
    unsigned short* __restrict__ Vb,
    int M, int N, int K)
{
    __shared__ __attribute__((aligned(16))) unsigned short As[BM * BK];
    __shared__ __attribute__((aligned(16))) unsigned short Bs[BN * BK];

    const float* W;  const float* bias;
    if (blockIdx.z == 0)      { W = Wq; bias = bq; }
    else if (blockIdx.z == 1) { W = Wk; bias = bk; }
    else                      { W = Wv; bias = bv; }

    const int tid  = threadIdx.x;
    const int wave = tid >> 6;
    const int lane = tid & 63;

    const int mBlock = blockIdx.y * BM;
    const int nBlock = blockIdx.x * BN;

    // staging: thread t -> row t>>1 (0..127), 16-elem chunk at col (t&1)*16
    const int sRow = tid >> 1;
    const int sCol = (tid & 1) * 16;
    const float* Ag = X + (size_t)(mBlock + sRow) * K + sCol;
    const float* Bg = W + (size_t)(nBlock + sRow) * K + sCol;
    unsigned short* Al = &As[sRow * BK + sCol];
    unsigned short* Bl = &Bs[sRow * BK + sCol];

    floatx4 acc[4][4] = {};

    const int wm   = (wave >> 1) * 64;
    const int wn   = (wave & 1) * 64;
    const int fRow = lane & 15;
    const int fK   = (lane >> 4) * 8;

    for (int kt = 0; kt < K; kt += BK) {
        floatx4 a[4], b[4];
        #pragma unroll
        for (int c = 0; c < 4; c++) {
            a[c] = *(const floatx4*)(Ag + kt + c * 4);
            b[c] = *(const floatx4*)(Bg + kt + c * 4);
        }
        __syncthreads();            // previous iter's LDS reads complete
        *(shortx8*)(Al)     = pack8(a[0], a[1]);
        *(shortx8*)(Al + 8) = pack8(a[2], a[3]);
        *(shortx8*)(Bl)     = pack8(b[0], b[1]);
        *(shortx8*)(Bl + 8) = pack8(b[2], b[3]);
        __syncthreads();            // staging visible block-wide

        shortx8 af[4], bfr[4];
        #pragma unroll
        for (int i = 0; i < 4; i++) {
            af[i]  = *(const shortx8*)&As[(wm + i*16 + fRow) * BK + fK];
            bfr[i] = *(const shortx8*)&Bs[(wn + i*16 + fRow) * BK + fK];
        }
        #pragma unroll
        for (int i = 0; i < 4; i++)
            #pragma unroll
            for (int j = 0; j < 4; j++)
                acc[i][j] = __builtin_amdgcn_mfma_f32_16x16x32_bf16(
                    af[i], bfr[j], acc[i][j], 0, 0, 0);
    }

    // C/D layout (m89/m91-verified): col = lane&15, row = (lane>>4)*4 + reg
    const int cRow = (lane >> 4) * 4;
    const int cCol = lane & 15;
    if (blockIdx.z == 0) {
        #pragma unroll
        for (int j = 0; j < 4; j++) {
            const int col = nBlock + wn + j*16 + cCol;
            const float bvf = bias[col];
            #pragma unroll
            for (int i = 0; i < 4; i++)
                #pragma unroll
                for (int r = 0; r < 4; r++) {
                    const int row = mBlock + wm + i*16 + cRow + r;
                    Qf[(size_t)row * N + col] = acc[i][j][r] + bvf;
                }
        }
    } else {
        unsigned short* Out = (blockIdx.z == 1) ? Kb : Vb;
        #pragma unroll
        for (int j = 0; j < 4; j++) {
            const int col = nBlock + wn + j*16 + cCol;
            const float bvf = bias[col];
            #pragma unroll
            for (int i = 0; i < 4; i++)
                #pragma unroll
                for (int r = 0; r < 4; r++) {
                    const int row = mBlock + wm + i*16 + cRow + r;
                    Out[(size_t)row * N + col] = f2bf(acc[i][j][r] + bvf);
                }
        }
    }
}

// One block per (p, b). 128 threads, 3 bf16-pairs of D=768 each.
// Q is fp32 in d_out; each thread reads exactly the q elements it later
// overwrites (and the block-wide barrier in the reduction orders all reads
// before all writes anyway), so in-place is safe.
__global__ __launch_bounds__(128) void sample_attend(
    const float* __restrict__ Q,
    const unsigned short* __restrict__ Kb,
    const unsigned short* __restrict__ Vb,
    const float* __restrict__ normx,
    const float* __restrict__ normy,
    const int* __restrict__ img_ids,
    const float* __restrict__ avgs,
    const float* __restrict__ stds,
    float* __restrict__ out)
{
    const int p   = blockIdx.x;   // 0..195
    const int b   = blockIdx.y;   // 0..127
    const int tid = threadIdx.x;
    const int id  = img_ids[b];

    // grid flat = [sx(196), sy(196)] reshaped (14,14,2): gx=flat[2p], gy=flat[2p+1]
    auto coord = [&](int n) -> float {
        int c = 0;
        if (n >= 196) { n -= 196; c = 1; }
        const float base = (c == 0) ? normx[b*196 + n] : normy[b*196 + n];
        const float a = avgs[(size_t)id*392 + c*196 + n];
        const float s = stds[(size_t)id*392 + c*196 + n];
        return tanhf((base + a) * s);
    };
    const float gx = coord(2*p);
    const float gy = coord(2*p + 1);

    const float ix = ((gx + 1.0f) * 14.0f - 1.0f) * 0.5f;
    const float iy = ((gy + 1.0f) * 14.0f - 1.0f) * 0.5f;
    const float x0f = floorf(ix), y0f = floorf(iy);
    const float wx1 = ix - x0f, wx0 = 1.0f - wx1;
    const float wy1 = iy - y0f, wy0 = 1.0f - wy1;
    const int x0 = (int)x0f, y0 = (int)y0f;

    float w[4]; int rr[4];
    {
        const int xs[4] = {x0, x0+1, x0, x0+1};
        const int ys[4] = {y0, y0, y0+1, y0+1};
        const float ws4[4] = {wx0*wy0, wx1*wy0, wx0*wy1, wx1*wy1};
        #pragma unroll
        for (int c = 0; c < 4; c++) {
            const bool valid = xs[c] >= 0 && xs[c] <= 13 && ys[c] >= 0 && ys[c] <= 13;
            w[c]  = valid ? ws4[c] : 0.0f;
            rr[c] = valid ? (ys[c]*14 + xs[c]) : 0;
        }
    }

    const size_t rowQ = ((size_t)b*196 + p) * 768;
    const unsigned short* kb = Kb + (size_t)b * 196 * 768;
    const unsigned short* vb = Vb + (size_t)b * 196 * 768;

    float sv0[3], sv1[3];
    float partial = 0.0f;
    #pragma unroll
    for (int i = 0; i < 3; i++) {
        const int d = (tid + i*128) * 2;
        float k0 = 0.f, k1 = 0.f, v0 = 0.f, v1 = 0.f;
        #pragma unroll
        for (int c = 0; c < 4; c++) {
            const unsigned int kw = *(const unsigned int*)&kb[rr[c]*768 + d];
            const unsigned int vw = *(const unsigned int*)&vb[rr[c]*768 + d];
            k0 += w[c] * bf2f((unsigned short)kw);
            k1 += w[c] * bf2f((unsigned short)(kw >> 16));
            v0 += w[c] * bf2f((unsigned short)vw);
            v1 += w[c] * bf2f((unsigned short)(vw >> 16));
        }
        const floatx2 qw = *(const floatx2*)&Q[rowQ + d];
        partial += k0 * qw.x + k1 * qw.y;
        sv0[i] = v0; sv1[i] = v1;
    }

    // 128-thread reduce: wave64 butterfly + 2-wave LDS combine
    #pragma unroll
    for (int off = 32; off >= 1; off >>= 1)
        partial += __shfl_xor(partial, off, 64);
    __shared__ float red[2];
    if ((tid & 63) == 0) red[tid >> 6] = partial;
    __syncthreads();
    const float score = red[0] + red[1];
    const float sig = 1.0f / (1.0f + expf(-0.01f * score));

    #pragma unroll
    for (int i = 0; i < 3; i++) {
        const int d = (tid + i*128) * 2;
        floatx2 o; o.x = sig * sv0[i]; o.y = sig * sv1[i];
        *(floatx2*)&out[rowQ + d] = o;
    }
}

extern "C" void kernel_launch(void* const* d_in, const int* in_sizes, int n_in,
                              void* d_out, int out_size, void* d_ws, size_t ws_size,
                              hipStream_t stream) {
    const float* x     = (const float*)d_in[0];
    const int*   ids   = (const int*)d_in[1];
    // d_in[2] = mask (unused by reference)
    const float* normx = (const float*)d_in[3];
    const float* normy = (const float*)d_in[4];
    const float* Wq    = (const float*)d_in[5];
    const float* bq    = (const float*)d_in[6];
    const float* Wk    = (const float*)d_in[7];
    const float* bk    = (const float*)d_in[8];
    const float* Wv    = (const float*)d_in[9];
    const float* bv    = (const float*)d_in[10];
    const float* avgs  = (const float*)d_in[11];
    const float* stds  = (const float*)d_in[12];
    float* out = (float*)d_out;

    const int B = 128, P = 196, D = 768;
    const int M = B * P;                      // 25088
    const size_t qkvElems = (size_t)M * D;    // 19,267,584

    float* q = out;                           // q fp32 lives in d_out
    unsigned short* k = (unsigned short*)d_ws;            // bf16
    unsigned short* v = k + qkvElems;                     // bf16

    dim3 gGemm(D / BN, M / BM, 3);            // (6, 196, 3)
    gemm_qkv<<<gGemm, 256, 0, stream>>>(x, Wq, Wk, Wv, bq, bk, bv, q, k, v, M, D, D);

    dim3 gS(P, B);                            // (196, 128)
    sample_attend<<<gS, 128, 0, stream>>>(q, k, v, normx, normy, ids, avgs, stds, out);
}

// Round 4
// 381.710 us; speedup vs baseline: 1.2177x; 1.2177x over previous
//
#include <hip/hip_runtime.h>
#include <hip/hip_bf16.h>

typedef __attribute__((ext_vector_type(4))) float floatx4;
typedef __attribute__((ext_vector_type(8))) short shortx8;
typedef __attribute__((address_space(3))) void as3_void;
typedef const __attribute__((address_space(1))) void as1_void;

__device__ __forceinline__ unsigned short f2bf(float f) {
    unsigned int u; __builtin_memcpy(&u, &f, 4);
    u += 0x7FFFu + ((u >> 16) & 1u);   // RNE
    return (unsigned short)(u >> 16);
}
__device__ __forceinline__ float bf2f(unsigned short h) {
    unsigned int u = ((unsigned int)h) << 16;
    float f; __builtin_memcpy(&f, &u, 4); return f;
}
__device__ __forceinline__ shortx8 pack8(floatx4 lo, floatx4 hi) {
    shortx8 r;
    r[0] = (short)f2bf(lo[0]); r[1] = (short)f2bf(lo[1]);
    r[2] = (short)f2bf(lo[2]); r[3] = (short)f2bf(lo[3]);
    r[4] = (short)f2bf(hi[0]); r[5] = (short)f2bf(hi[1]);
    r[6] = (short)f2bf(hi[2]); r[7] = (short)f2bf(hi[3]);
    return r;
}
__device__ __forceinline__ void ld16(const unsigned short* g, unsigned short* l) {
    __builtin_amdgcn_global_load_lds((as1_void*)g, (as3_void*)l, 16, 0, 0);
}

#define BM 128
#define BN 128
#define BK 32

// ---------- fp32 -> bf16 pre-convert (4 segments in one launch) ----------
__global__ __launch_bounds__(256) void cvt4(
    const float* __restrict__ s0, const float* __restrict__ s1,
    const float* __restrict__ s2, const float* __restrict__ s3,
    unsigned short* __restrict__ d0, unsigned short* __restrict__ d1,
    unsigned short* __restrict__ d2, unsigned short* __restrict__ d3,
    int nb0, int nb1, int nb2)
{
    int bid = blockIdx.x;
    const float* s; unsigned short* d;
    if (bid < nb0)                  { s = s0; d = d0; }
    else if (bid < nb0 + nb1)       { s = s1; d = d1; bid -= nb0; }
    else if (bid < nb0 + nb1 + nb2) { s = s2; d = d2; bid -= nb0 + nb1; }
    else                            { s = s3; d = d3; bid -= nb0 + nb1 + nb2; }
    const size_t i = ((size_t)bid * 256 + threadIdx.x) * 8;
    const floatx4 lo = *(const floatx4*)(s + i);
    const floatx4 hi = *(const floatx4*)(s + i + 4);
    *(shortx8*)(d + i) = pack8(lo, hi);
}

// ---------- fast GEMM: pure-bf16 m97 structure (global_load_lds w=16) ----------
// q/k/v = Xb (MxK bf16) * Wb[z]^T (NxK bf16) + bias(fp32).
// z==0 stores q as fp32 into d_out; z==1/2 store bf16 k/v into ws.
__global__ __launch_bounds__(256) void gemm_qkv_bf16(
    const unsigned short* __restrict__ Xb,
    const unsigned short* __restrict__ Wb,   // 3 contiguous NxK mats
    const float* __restrict__ bq, const float* __restrict__ bk,
    const float* __restrict__ bv,
    float* __restrict__ Qf, unsigned short* __restrict__ Kb,
    unsigned short* __restrict__ Vb,
    int M, int N, int K)
{
    __shared__ __attribute__((aligned(16))) unsigned short As[BM * BK];
    __shared__ __attribute__((aligned(16))) unsigned short Bs[BN * BK];

    const int z = blockIdx.z;
    const unsigned short* W = Wb + (size_t)z * N * K;
    const float* bias = (z == 0) ? bq : ((z == 1) ? bk : bv);

    const int tid  = threadIdx.x;
    const int wave = tid >> 6;
    const int lane = tid & 63;

    const int mBlock = blockIdx.y * BM;
    const int nBlock = blockIdx.x * BN;

    // staging: thread t -> row t>>2 (and +64), 8-elem chunk (t&3)*8.
    // LDS dest elem offset = wave*512 + lane*8  (wave-uniform base + lane*16B) ✓
    const int sRow   = tid >> 2;
    const int sChunk = (tid & 3) * 8;
    const unsigned short* Ag = Xb + (size_t)(mBlock + sRow) * K + sChunk;
    const unsigned short* Bg = W  + (size_t)(nBlock + sRow) * K + sChunk;
    unsigned short* Al = &As[sRow * BK + sChunk];
    unsigned short* Bl = &Bs[sRow * BK + sChunk];

    floatx4 acc[4][4] = {};

    const int wm   = (wave >> 1) * 64;
    const int wn   = (wave & 1) * 64;
    const int fRow = lane & 15;
    const int fK   = (lane >> 4) * 8;

    for (int kt = 0; kt < K; kt += BK) {
        ld16(Ag + kt,                Al);
        ld16(Ag + kt + (size_t)64*K, Al + 64 * BK);
        ld16(Bg + kt,                Bl);
        ld16(Bg + kt + (size_t)64*K, Bl + 64 * BK);
        __syncthreads();                    // drains vmcnt before barrier

        shortx8 af[4], bfr[4];
        #pragma unroll
        for (int i = 0; i < 4; i++) {
            af[i]  = *(const shortx8*)&As[(wm + i*16 + fRow) * BK + fK];
            bfr[i] = *(const shortx8*)&Bs[(wn + i*16 + fRow) * BK + fK];
        }
        #pragma unroll
        for (int i = 0; i < 4; i++)
            #pragma unroll
            for (int j = 0; j < 4; j++)
                acc[i][j] = __builtin_amdgcn_mfma_f32_16x16x32_bf16(
                    af[i], bfr[j], acc[i][j], 0, 0, 0);
        __syncthreads();                    // LDS reads done before next stage
    }

    // C/D layout: col = lane&15, row = (lane>>4)*4 + reg
    const int cRow = (lane >> 4) * 4;
    const int cCol = lane & 15;
    if (z == 0) {
        #pragma unroll
        for (int j = 0; j < 4; j++) {
            const int col = nBlock + wn + j*16 + cCol;
            const float bvf = bias[col];
            #pragma unroll
            for (int i = 0; i < 4; i++)
                #pragma unroll
                for (int r = 0; r < 4; r++)
                    Qf[(size_t)(mBlock + wm + i*16 + cRow + r) * N + col] =
                        acc[i][j][r] + bvf;
        }
    } else {
        unsigned short* Out = (z == 1) ? Kb : Vb;
        #pragma unroll
        for (int j = 0; j < 4; j++) {
            const int col = nBlock + wn + j*16 + cCol;
            const float bvf = bias[col];
            #pragma unroll
            for (int i = 0; i < 4; i++)
                #pragma unroll
                for (int r = 0; r < 4; r++)
                    Out[(size_t)(mBlock + wm + i*16 + cRow + r) * N + col] =
                        f2bf(acc[i][j][r] + bvf);
        }
    }
}

// ---------- fallback GEMM (round-3 proven): fp32 src, pack in kernel ----------
__global__ __launch_bounds__(256) void gemm_qkv_f32(
    const float* __restrict__ X,
    const float* __restrict__ Wq, const float* __restrict__ Wk,
    const float* __restrict__ Wv,
    const float* __restrict__ bq, const float* __restrict__ bk,
    const float* __restrict__ bv,
    float* __restrict__ Qf, unsigned short* __restrict__ Kb,
    unsigned short* __restrict__ Vb,
    int M, int N, int K)
{
    __shared__ __attribute__((aligned(16))) unsigned short As[BM * BK];
    __shared__ __attribute__((aligned(16))) unsigned short Bs[BN * BK];

    const float* W;  const float* bias;
    if (blockIdx.z == 0)      { W = Wq; bias = bq; }
    else if (blockIdx.z == 1) { W = Wk; bias = bk; }
    else                      { W = Wv; bias = bv; }

    const int tid  = threadIdx.x;
    const int wave = tid >> 6;
    const int lane = tid & 63;
    const int mBlock = blockIdx.y * BM;
    const int nBlock = blockIdx.x * BN;

    const int sRow = tid >> 1;
    const int sCol = (tid & 1) * 16;
    const float* Ag = X + (size_t)(mBlock + sRow) * K + sCol;
    const float* Bg = W + (size_t)(nBlock + sRow) * K + sCol;
    unsigned short* Al = &As[sRow * BK + sCol];
    unsigned short* Bl = &Bs[sRow * BK + sCol];

    floatx4 acc[4][4] = {};
    const int wm   = (wave >> 1) * 64;
    const int wn   = (wave & 1) * 64;
    const int fRow = lane & 15;
    const int fK   = (lane >> 4) * 8;

    for (int kt = 0; kt < K; kt += BK) {
        floatx4 a[4], b[4];
        #pragma unroll
        for (int c = 0; c < 4; c++) {
            a[c] = *(const floatx4*)(Ag + kt + c * 4);
            b[c] = *(const floatx4*)(Bg + kt + c * 4);
        }
        __syncthreads();
        *(shortx8*)(Al)     = pack8(a[0], a[1]);
        *(shortx8*)(Al + 8) = pack8(a[2], a[3]);
        *(shortx8*)(Bl)     = pack8(b[0], b[1]);
        *(shortx8*)(Bl + 8) = pack8(b[2], b[3]);
        __syncthreads();

        shortx8 af[4], bfr[4];
        #pragma unroll
        for (int i = 0; i < 4; i++) {
            af[i]  = *(const shortx8*)&As[(wm + i*16 + fRow) * BK + fK];
            bfr[i] = *(const shortx8*)&Bs[(wn + i*16 + fRow) * BK + fK];
        }
        #pragma unroll
        for (int i = 0; i < 4; i++)
            #pragma unroll
            for (int j = 0; j < 4; j++)
                acc[i][j] = __builtin_amdgcn_mfma_f32_16x16x32_bf16(
                    af[i], bfr[j], acc[i][j], 0, 0, 0);
    }

    const int cRow = (lane >> 4) * 4;
    const int cCol = lane & 15;
    if (blockIdx.z == 0) {
        #pragma unroll
        for (int j = 0; j < 4; j++) {
            const int col = nBlock + wn + j*16 + cCol;
            const float bvf = bias[col];
            #pragma unroll
            for (int i = 0; i < 4; i++)
                #pragma unroll
                for (int r = 0; r < 4; r++)
                    Qf[(size_t)(mBlock + wm + i*16 + cRow + r) * N + col] =
                        acc[i][j][r] + bvf;
        }
    } else {
        unsigned short* Out = (blockIdx.z == 1) ? Kb : Vb;
        #pragma unroll
        for (int j = 0; j < 4; j++) {
            const int col = nBlock + wn + j*16 + cCol;
            const float bvf = bias[col];
            #pragma unroll
            for (int i = 0; i < 4; i++)
                #pragma unroll
                for (int r = 0; r < 4; r++)
                    Out[(size_t)(mBlock + wm + i*16 + cRow + r) * N + col] =
                        f2bf(acc[i][j][r] + bvf);
        }
    }
}

// ---------- sampler: one wave per (b,p), no barriers, wide gathers ----------
__global__ __launch_bounds__(128) void sample_attend(
    const float* __restrict__ Q,
    const unsigned short* __restrict__ Kb,
    const unsigned short* __restrict__ Vb,
    const float* __restrict__ normx,
    const float* __restrict__ normy,
    const int* __restrict__ img_ids,
    const float* __restrict__ avgs,
    const float* __restrict__ stds,
    float* __restrict__ out)
{
    const int w    = threadIdx.x >> 6;           // wave in block
    const int lane = threadIdx.x & 63;
    const int p    = blockIdx.x * 2 + w;         // 0..195
    const int b    = blockIdx.y;                 // 0..127
    const int id   = img_ids[b];

    // grid flat = [sx(196), sy(196)]: gx = flat[2p], gy = flat[2p+1]
    auto coord = [&](int n) -> float {
        int c = 0;
        if (n >= 196) { n -= 196; c = 1; }
        const float base = (c == 0) ? normx[b*196 + n] : normy[b*196 + n];
        const float a = avgs[(size_t)id*392 + c*196 + n];
        const float s = stds[(size_t)id*392 + c*196 + n];
        return tanhf((base + a) * s);
    };
    const float gx = coord(2*p);
    const float gy = coord(2*p + 1);

    const float ix = ((gx + 1.0f) * 14.0f - 1.0f) * 0.5f;
    const float iy = ((gy + 1.0f) * 14.0f - 1.0f) * 0.5f;
    const float x0f = floorf(ix), y0f = floorf(iy);
    const float wx1 = ix - x0f, wx0 = 1.0f - wx1;
    const float wy1 = iy - y0f, wy0 = 1.0f - wy1;
    const int x0 = (int)x0f, y0 = (int)y0f;

    float cw[4]; int rr[4];
    {
        const int xs[4] = {x0, x0+1, x0, x0+1};
        const int ys[4] = {y0, y0, y0+1, y0+1};
        const float ws4[4] = {wx0*wy0, wx1*wy0, wx0*wy1, wx1*wy1};
        #pragma unroll
        for (int c = 0; c < 4; c++) {
            const bool valid = xs[c] >= 0 && xs[c] <= 13 && ys[c] >= 0 && ys[c] <= 13;
            cw[c] = valid ? ws4[c] : 0.0f;
            rr[c] = valid ? (ys[c]*14 + xs[c]) * 768 : 0;
        }
    }

    const size_t rowQ = ((size_t)b*196 + p) * 768;
    const unsigned short* kb = Kb + (size_t)b * 196 * 768;
    const unsigned short* vb = Vb + (size_t)b * 196 * 768;

    floatx4 pv[3];
    float partial = 0.0f;
    #pragma unroll
    for (int j = 0; j < 3; j++) {
        const int d = lane * 4 + j * 256;        // 4 elems / lane / j
        floatx4 kx = {0.f, 0.f, 0.f, 0.f}, vx = {0.f, 0.f, 0.f, 0.f};
        #pragma unroll
        for (int c = 0; c < 4; c++) {
            const unsigned long long kw = *(const unsigned long long*)&kb[rr[c] + d];
            const unsigned long long vw = *(const unsigned long long*)&vb[rr[c] + d];
            #pragma unroll
            for (int e = 0; e < 4; e++) {
                kx[e] += cw[c] * bf2f((unsigned short)(kw >> (16*e)));
                vx[e] += cw[c] * bf2f((unsigned short)(vw >> (16*e)));
            }
        }
        const floatx4 q4 = *(const floatx4*)&Q[rowQ + d];
        partial += kx[0]*q4[0] + kx[1]*q4[1] + kx[2]*q4[2] + kx[3]*q4[3];
        pv[j] = vx;
    }

    #pragma unroll
    for (int off = 32; off >= 1; off >>= 1)
        partial += __shfl_xor(partial, off, 64);
    const float sig = 1.0f / (1.0f + expf(-0.01f * partial));

    #pragma unroll
    for (int j = 0; j < 3; j++) {
        floatx4 o;
        o[0] = sig * pv[j][0]; o[1] = sig * pv[j][1];
        o[2] = sig * pv[j][2]; o[3] = sig * pv[j][3];
        *(floatx4*)&out[rowQ + lane * 4 + j * 256] = o;
    }
}

extern "C" void kernel_launch(void* const* d_in, const int* in_sizes, int n_in,
                              void* d_out, int out_size, void* d_ws, size_t ws_size,
                              hipStream_t stream) {
    const float* x     = (const float*)d_in[0];
    const int*   ids   = (const int*)d_in[1];
    // d_in[2] = mask (unused by reference)
    const float* normx = (const float*)d_in[3];
    const float* normy = (const float*)d_in[4];
    const float* Wq    = (const float*)d_in[5];
    const float* bq    = (const float*)d_in[6];
    const float* Wk    = (const float*)d_in[7];
    const float* bk    = (const float*)d_in[8];
    const float* Wv    = (const float*)d_in[9];
    const float* bv    = (const float*)d_in[10];
    const float* avgs  = (const float*)d_in[11];
    const float* stds  = (const float*)d_in[12];
    float* out = (float*)d_out;

    const int B = 128, P = 196, D = 768;
    const int M = B * P;                         // 25088
    const size_t qkvElems = (size_t)M * D;       // 19,267,584
    const size_t wElems   = (size_t)D * D;       // 589,824

    float* q = out;                              // q fp32 lives in d_out

    // fast path needs: Xb + 3*W (bf16) + k + v (bf16)
    const size_t needBytes = (qkvElems + 3 * wElems + 2 * qkvElems) * 2;

    if (ws_size >= needBytes) {
        unsigned short* Xb = (unsigned short*)d_ws;
        unsigned short* Wb = Xb + qkvElems;
        unsigned short* k  = Wb + 3 * wElems;
        unsigned short* v  = k + qkvElems;

        const int nbX = (int)(qkvElems / 8 / 256);   // 9408
        const int nbW = (int)(wElems / 8 / 256);     // 288
        cvt4<<<nbX + 3 * nbW, 256, 0, stream>>>(
            x, Wq, Wk, Wv, Xb, Wb, Wb + wElems, Wb + 2 * wElems, nbX, nbW, nbW);

        dim3 gGemm(D / BN, M / BM, 3);
        gemm_qkv_bf16<<<gGemm, 256, 0, stream>>>(
            Xb, Wb, bq, bk, bv, q, k, v, M, D, D);

        dim3 gS(P / 2, B);
        sample_attend<<<gS, 128, 0, stream>>>(
            q, k, v, normx, normy, ids, avgs, stds, out);
    } else {
        unsigned short* k = (unsigned short*)d_ws;
        unsigned short* v = k + qkvElems;

        dim3 gGemm(D / BN, M / BM, 3);
        gemm_qkv_f32<<<gGemm, 256, 0, stream>>>(
            x, Wq, Wk, Wv, bq, bk, bv, q, k, v, M, D, D);

        dim3 gS(P / 2, B);
        sample_attend<<<gS, 128, 0, stream>>>(
            q, k, v, normx, normy, ids, avgs, stds, out);
    }
}

// Round 5
// 364.445 us; speedup vs baseline: 1.2754x; 1.0474x over previous
//
#include <hip/hip_runtime.h>
#include <hip/hip_bf16.h>

typedef __attribute__((ext_vector_type(4))) float floatx4;
typedef __attribute__((ext_vector_type(8))) short shortx8;
typedef __attribute__((address_space(3))) void as3_void;
typedef const __attribute__((address_space(1))) void as1_void;

__device__ __forceinline__ unsigned short f2bf(float f) {
    unsigned int u; __builtin_memcpy(&u, &f, 4);
    u += 0x7FFFu + ((u >> 16) & 1u);   // RNE
    return (unsigned short)(u >> 16);
}
__device__ __forceinline__ float bf2f(unsigned short h) {
    unsigned int u = ((unsigned int)h) << 16;
    float f; __builtin_memcpy(&f, &u, 4); return f;
}
__device__ __forceinline__ shortx8 pack8(floatx4 lo, floatx4 hi) {
    shortx8 r;
    r[0] = (short)f2bf(lo[0]); r[1] = (short)f2bf(lo[1]);
    r[2] = (short)f2bf(lo[2]); r[3] = (short)f2bf(lo[3]);
    r[4] = (short)f2bf(hi[0]); r[5] = (short)f2bf(hi[1]);
    r[6] = (short)f2bf(hi[2]); r[7] = (short)f2bf(hi[3]);
    return r;
}
__device__ __forceinline__ void ld16(const unsigned short* g, unsigned short* l) {
    __builtin_amdgcn_global_load_lds((as1_void*)g, (as3_void*)l, 16, 0, 0);
}

#define BM 128
#define BN 128
#define BK 32

// ---------- fp32 -> bf16 pre-convert (4 segments in one launch) ----------
__global__ __launch_bounds__(256) void cvt4(
    const float* __restrict__ s0, const float* __restrict__ s1,
    const float* __restrict__ s2, const float* __restrict__ s3,
    unsigned short* __restrict__ d0, unsigned short* __restrict__ d1,
    unsigned short* __restrict__ d2, unsigned short* __restrict__ d3,
    int nb0, int nb1, int nb2)
{
    int bid = blockIdx.x;
    const float* s; unsigned short* d;
    if (bid < nb0)                  { s = s0; d = d0; }
    else if (bid < nb0 + nb1)       { s = s1; d = d1; bid -= nb0; }
    else if (bid < nb0 + nb1 + nb2) { s = s2; d = d2; bid -= nb0 + nb1; }
    else                            { s = s3; d = d3; bid -= nb0 + nb1 + nb2; }
    const size_t i = ((size_t)bid * 256 + threadIdx.x) * 8;
    const floatx4 lo = *(const floatx4*)(s + i);
    const floatx4 hi = *(const floatx4*)(s + i + 4);
    *(shortx8*)(d + i) = pack8(lo, hi);
}

// ---------- fast GEMM: pure-bf16 m97 structure (global_load_lds w=16) ----------
// q/k/v = Xb (MxK bf16) * Wb[z]^T (NxK bf16) + bias(fp32).
// z==0: q -> bf16 ws (Qb16 != null) or fp32 d_out. z==1/2: bf16 k/v in ws.
__global__ __launch_bounds__(256) void gemm_qkv_bf16(
    const unsigned short* __restrict__ Xb,
    const unsigned short* __restrict__ Wb,   // 3 contiguous NxK mats
    const float* __restrict__ bq, const float* __restrict__ bk,
    const float* __restrict__ bv,
    float* __restrict__ Qf, unsigned short* __restrict__ Qb16,
    unsigned short* __restrict__ Kb, unsigned short* __restrict__ Vb,
    int M, int N, int K)
{
    __shared__ __attribute__((aligned(16))) unsigned short As[BM * BK];
    __shared__ __attribute__((aligned(16))) unsigned short Bs[BN * BK];

    const int z = blockIdx.z;
    const unsigned short* W = Wb + (size_t)z * N * K;
    const float* bias = (z == 0) ? bq : ((z == 1) ? bk : bv);

    const int tid  = threadIdx.x;
    const int wave = tid >> 6;
    const int lane = tid & 63;

    const int mBlock = blockIdx.y * BM;
    const int nBlock = blockIdx.x * BN;

    // staging: thread t -> row t>>2 (and +64), 8-elem chunk (t&3)*8.
    // LDS dest elem offset = wave*512 + lane*8 (wave-uniform base + lane*16B) ✓
    const int sRow   = tid >> 2;
    const int sChunk = (tid & 3) * 8;
    const unsigned short* Ag = Xb + (size_t)(mBlock + sRow) * K + sChunk;
    const unsigned short* Bg = W  + (size_t)(nBlock + sRow) * K + sChunk;
    unsigned short* Al = &As[sRow * BK + sChunk];
    unsigned short* Bl = &Bs[sRow * BK + sChunk];

    floatx4 acc[4][4] = {};

    const int wm   = (wave >> 1) * 64;
    const int wn   = (wave & 1) * 64;
    const int fRow = lane & 15;
    const int fK   = (lane >> 4) * 8;

    for (int kt = 0; kt < K; kt += BK) {
        ld16(Ag + kt,                Al);
        ld16(Ag + kt + (size_t)64*K, Al + 64 * BK);
        ld16(Bg + kt,                Bl);
        ld16(Bg + kt + (size_t)64*K, Bl + 64 * BK);
        __syncthreads();                    // drains vmcnt before barrier

        shortx8 af[4], bfr[4];
        #pragma unroll
        for (int i = 0; i < 4; i++) {
            af[i]  = *(const shortx8*)&As[(wm + i*16 + fRow) * BK + fK];
            bfr[i] = *(const shortx8*)&Bs[(wn + i*16 + fRow) * BK + fK];
        }
        #pragma unroll
        for (int i = 0; i < 4; i++)
            #pragma unroll
            for (int j = 0; j < 4; j++)
                acc[i][j] = __builtin_amdgcn_mfma_f32_16x16x32_bf16(
                    af[i], bfr[j], acc[i][j], 0, 0, 0);
        __syncthreads();                    // LDS reads done before next stage
    }

    // C/D layout: col = lane&15, row = (lane>>4)*4 + reg
    const int cRow = (lane >> 4) * 4;
    const int cCol = lane & 15;
    if (z == 0 && Qb16 == nullptr) {
        #pragma unroll
        for (int j = 0; j < 4; j++) {
            const int col = nBlock + wn + j*16 + cCol;
            const float bvf = bias[col];
            #pragma unroll
            for (int i = 0; i < 4; i++)
                #pragma unroll
                for (int r = 0; r < 4; r++)
                    Qf[(size_t)(mBlock + wm + i*16 + cRow + r) * N + col] =
                        acc[i][j][r] + bvf;
        }
    } else {
        unsigned short* Out = (z == 0) ? Qb16 : ((z == 1) ? Kb : Vb);
        #pragma unroll
        for (int j = 0; j < 4; j++) {
            const int col = nBlock + wn + j*16 + cCol;
            const float bvf = bias[col];
            #pragma unroll
            for (int i = 0; i < 4; i++)
                #pragma unroll
                for (int r = 0; r < 4; r++)
                    Out[(size_t)(mBlock + wm + i*16 + cRow + r) * N + col] =
                        f2bf(acc[i][j][r] + bvf);
        }
    }
}

// ---------- fallback GEMM (round-3 proven): fp32 src, pack in kernel ----------
__global__ __launch_bounds__(256) void gemm_qkv_f32(
    const float* __restrict__ X,
    const float* __restrict__ Wq, const float* __restrict__ Wk,
    const float* __restrict__ Wv,
    const float* __restrict__ bq, const float* __restrict__ bk,
    const float* __restrict__ bv,
    float* __restrict__ Qf, unsigned short* __restrict__ Kb,
    unsigned short* __restrict__ Vb,
    int M, int N, int K)
{
    __shared__ __attribute__((aligned(16))) unsigned short As[BM * BK];
    __shared__ __attribute__((aligned(16))) unsigned short Bs[BN * BK];

    const float* W;  const float* bias;
    if (blockIdx.z == 0)      { W = Wq; bias = bq; }
    else if (blockIdx.z == 1) { W = Wk; bias = bk; }
    else                      { W = Wv; bias = bv; }

    const int tid  = threadIdx.x;
    const int wave = tid >> 6;
    const int lane = tid & 63;
    const int mBlock = blockIdx.y * BM;
    const int nBlock = blockIdx.x * BN;

    const int sRow = tid >> 1;
    const int sCol = (tid & 1) * 16;
    const float* Ag = X + (size_t)(mBlock + sRow) * K + sCol;
    const float* Bg = W + (size_t)(nBlock + sRow) * K + sCol;
    unsigned short* Al = &As[sRow * BK + sCol];
    unsigned short* Bl = &Bs[sRow * BK + sCol];

    floatx4 acc[4][4] = {};
    const int wm   = (wave >> 1) * 64;
    const int wn   = (wave & 1) * 64;
    const int fRow = lane & 15;
    const int fK   = (lane >> 4) * 8;

    for (int kt = 0; kt < K; kt += BK) {
        floatx4 a[4], b[4];
        #pragma unroll
        for (int c = 0; c < 4; c++) {
            a[c] = *(const floatx4*)(Ag + kt + c * 4);
            b[c] = *(const floatx4*)(Bg + kt + c * 4);
        }
        __syncthreads();
        *(shortx8*)(Al)     = pack8(a[0], a[1]);
        *(shortx8*)(Al + 8) = pack8(a[2], a[3]);
        *(shortx8*)(Bl)     = pack8(b[0], b[1]);
        *(shortx8*)(Bl + 8) = pack8(b[2], b[3]);
        __syncthreads();

        shortx8 af[4], bfr[4];
        #pragma unroll
        for (int i = 0; i < 4; i++) {
            af[i]  = *(const shortx8*)&As[(wm + i*16 + fRow) * BK + fK];
            bfr[i] = *(const shortx8*)&Bs[(wn + i*16 + fRow) * BK + fK];
        }
        #pragma unroll
        for (int i = 0; i < 4; i++)
            #pragma unroll
            for (int j = 0; j < 4; j++)
                acc[i][j] = __builtin_amdgcn_mfma_f32_16x16x32_bf16(
                    af[i], bfr[j], acc[i][j], 0, 0, 0);
    }

    const int cRow = (lane >> 4) * 4;
    const int cCol = lane & 15;
    if (blockIdx.z == 0) {
        #pragma unroll
        for (int j = 0; j < 4; j++) {
            const int col = nBlock + wn + j*16 + cCol;
            const float bvf = bias[col];
            #pragma unroll
            for (int i = 0; i < 4; i++)
                #pragma unroll
                for (int r = 0; r < 4; r++)
                    Qf[(size_t)(mBlock + wm + i*16 + cRow + r) * N + col] =
                        acc[i][j][r] + bvf;
        }
    } else {
        unsigned short* Out = (blockIdx.z == 1) ? Kb : Vb;
        #pragma unroll
        for (int j = 0; j < 4; j++) {
            const int col = nBlock + wn + j*16 + cCol;
            const float bvf = bias[col];
            #pragma unroll
            for (int i = 0; i < 4; i++)
                #pragma unroll
                for (int r = 0; r < 4; r++)
                    Out[(size_t)(mBlock + wm + i*16 + cRow + r) * N + col] =
                        f2bf(acc[i][j][r] + bvf);
        }
    }
}

// ---------- sampler: one wave per (b,p), XCD-clustered b mapping ----------
// blockIdx%8 = XCD (dispatch round-robin heuristic); each XCD owns 16 b's and
// walks all 196 p's of one b before the next -> per-XCD L2 working set ~1.2 MB
// (k/v rows of 1-2 b's) instead of ~12 MB -> k/v fetched from HBM once.
__global__ __launch_bounds__(64) void sample_attend(
    const float* __restrict__ Qf,            // fp32 q (if Qb16 == null)
    const unsigned short* __restrict__ Qb16, // bf16 q (preferred)
    const unsigned short* __restrict__ Kb,
    const unsigned short* __restrict__ Vb,
    const float* __restrict__ normx,
    const float* __restrict__ normy,
    const int* __restrict__ img_ids,
    const float* __restrict__ avgs,
    const float* __restrict__ stds,
    float* __restrict__ out)
{
    const unsigned g    = blockIdx.x;
    const unsigned xcd  = g & 7;
    const unsigned slot = g >> 3;            // 0..3135
    const int b = (int)(xcd * 16 + slot / 196);
    const int p = (int)(slot % 196);
    const int lane = threadIdx.x;
    const int id = img_ids[b];

    // grid flat = [sx(196), sy(196)]: gx = flat[2p], gy = flat[2p+1]
    auto coord = [&](int n) -> float {
        int c = 0;
        if (n >= 196) { n -= 196; c = 1; }
        const float base = (c == 0) ? normx[b*196 + n] : normy[b*196 + n];
        const float a = avgs[(size_t)id*392 + c*196 + n];
        const float s = stds[(size_t)id*392 + c*196 + n];
        return tanhf((base + a) * s);
    };
    const float gx = coord(2*p);
    const float gy = coord(2*p + 1);

    const float ix = ((gx + 1.0f) * 14.0f - 1.0f) * 0.5f;
    const float iy = ((gy + 1.0f) * 14.0f - 1.0f) * 0.5f;
    const float x0f = floorf(ix), y0f = floorf(iy);
    const float wx1 = ix - x0f, wx0 = 1.0f - wx1;
    const float wy1 = iy - y0f, wy0 = 1.0f - wy1;
    const int x0 = (int)x0f, y0 = (int)y0f;

    float cw[4]; int rr[4];
    {
        const int xs[4] = {x0, x0+1, x0, x0+1};
        const int ys[4] = {y0, y0, y0+1, y0+1};
        const float ws4[4] = {wx0*wy0, wx1*wy0, wx0*wy1, wx1*wy1};
        #pragma unroll
        for (int c = 0; c < 4; c++) {
            const bool valid = xs[c] >= 0 && xs[c] <= 13 && ys[c] >= 0 && ys[c] <= 13;
            cw[c] = valid ? ws4[c] : 0.0f;
            rr[c] = valid ? (ys[c]*14 + xs[c]) * 768 : 0;
        }
    }

    const size_t rowOff = ((size_t)b*196 + p) * 768;
    const unsigned short* kb = Kb + (size_t)b * 196 * 768;
    const unsigned short* vb = Vb + (size_t)b * 196 * 768;

    floatx4 pv[3];
    float partial = 0.0f;
    #pragma unroll
    for (int j = 0; j < 3; j++) {
        const int d = lane * 4 + j * 256;        // 4 elems / lane / j
        floatx4 kx = {0.f, 0.f, 0.f, 0.f}, vx = {0.f, 0.f, 0.f, 0.f};
        #pragma unroll
        for (int c = 0; c < 4; c++) {
            const unsigned long long kw = *(const unsigned long long*)&kb[rr[c] + d];
            const unsigned long long vw = *(const unsigned long long*)&vb[rr[c] + d];
            #pragma unroll
            for (int e = 0; e < 4; e++) {
                kx[e] += cw[c] * bf2f((unsigned short)(kw >> (16*e)));
                vx[e] += cw[c] * bf2f((unsigned short)(vw >> (16*e)));
            }
        }
        floatx4 q4;
        if (Qb16 != nullptr) {
            const unsigned long long qw = *(const unsigned long long*)&Qb16[rowOff + d];
            q4[0] = bf2f((unsigned short)qw);
            q4[1] = bf2f((unsigned short)(qw >> 16));
            q4[2] = bf2f((unsigned short)(qw >> 32));
            q4[3] = bf2f((unsigned short)(qw >> 48));
        } else {
            q4 = *(const floatx4*)&Qf[rowOff + d];
        }
        partial += kx[0]*q4[0] + kx[1]*q4[1] + kx[2]*q4[2] + kx[3]*q4[3];
        pv[j] = vx;
    }

    #pragma unroll
    for (int off = 32; off >= 1; off >>= 1)
        partial += __shfl_xor(partial, off, 64);
    const float sig = 1.0f / (1.0f + expf(-0.01f * partial));

    #pragma unroll
    for (int j = 0; j < 3; j++) {
        floatx4 o;
        o[0] = sig * pv[j][0]; o[1] = sig * pv[j][1];
        o[2] = sig * pv[j][2]; o[3] = sig * pv[j][3];
        *(floatx4*)&out[rowOff + lane * 4 + j * 256] = o;
    }
}

extern "C" void kernel_launch(void* const* d_in, const int* in_sizes, int n_in,
                              void* d_out, int out_size, void* d_ws, size_t ws_size,
                              hipStream_t stream) {
    const float* x     = (const float*)d_in[0];
    const int*   ids   = (const int*)d_in[1];
    // d_in[2] = mask (unused by reference)
    const float* normx = (const float*)d_in[3];
    const float* normy = (const float*)d_in[4];
    const float* Wq    = (const float*)d_in[5];
    const float* bq    = (const float*)d_in[6];
    const float* Wk    = (const float*)d_in[7];
    const float* bk    = (const float*)d_in[8];
    const float* Wv    = (const float*)d_in[9];
    const float* bv    = (const float*)d_in[10];
    const float* avgs  = (const float*)d_in[11];
    const float* stds  = (const float*)d_in[12];
    float* out = (float*)d_out;

    const int B = 128, P = 196, D = 768;
    const int M = B * P;                         // 25088
    const size_t qkvElems = (size_t)M * D;       // 19,267,584
    const size_t wElems   = (size_t)D * D;       // 589,824

    // ws tiers (deterministic: ws_size constant across calls)
    const size_t tierA = (4 * qkvElems + 3 * wElems) * 2;  // +bf16 q  (~157.7 MB)
    const size_t tierB = (3 * qkvElems + 3 * wElems) * 2;  // bf16 X/W/k/v (~119 MB)

    const int nSampBlocks = 8 * 16 * P;          // 25088

    if (ws_size >= tierB) {
        unsigned short* Xb = (unsigned short*)d_ws;
        unsigned short* Wb = Xb + qkvElems;
        unsigned short* k  = Wb + 3 * wElems;
        unsigned short* v  = k + qkvElems;
        unsigned short* qb = (ws_size >= tierA) ? (v + qkvElems) : nullptr;
        float* qf = (qb == nullptr) ? out : nullptr;

        const int nbX = (int)(qkvElems / 8 / 256);   // 9408
        const int nbW = (int)(wElems / 8 / 256);     // 288
        cvt4<<<nbX + 3 * nbW, 256, 0, stream>>>(
            x, Wq, Wk, Wv, Xb, Wb, Wb + wElems, Wb + 2 * wElems, nbX, nbW, nbW);

        dim3 gGemm(D / BN, M / BM, 3);
        gemm_qkv_bf16<<<gGemm, 256, 0, stream>>>(
            Xb, Wb, bq, bk, bv, qf, qb, k, v, M, D, D);

        sample_attend<<<nSampBlocks, 64, 0, stream>>>(
            qf, qb, k, v, normx, normy, ids, avgs, stds, out);
    } else {
        unsigned short* k = (unsigned short*)d_ws;
        unsigned short* v = k + qkvElems;

        dim3 gGemm(D / BN, M / BM, 3);
        gemm_qkv_f32<<<gGemm, 256, 0, stream>>>(
            x, Wq, Wk, Wv, bq, bk, bv, out, k, v, M, D, D);

        sample_attend<<<nSampBlocks, 64, 0, stream>>>(
            out, nullptr, k, v, normx, normy, ids, avgs, stds, out);
    }
}